// Round 7
// baseline (162.005 us; speedup 1.0000x reference)
//
#include <hip/hip_runtime.h>

#define B_ 4
#define L_ 2048
#define DM 512
#define DI 1024
#define DS 16
#define DR 32
#define M_ (B_ * L_)

#define CHUNK 32
#define CL (L_ / CHUNK)   // 64 timesteps per chunk

typedef unsigned short ushort_t;
typedef __attribute__((ext_vector_type(8))) short short8;
typedef __attribute__((ext_vector_type(4))) float floatx4;
typedef __attribute__((ext_vector_type(4))) unsigned int uint4v;

__device__ __forceinline__ float bf2f(ushort_t u) {
    union { unsigned int i; float f; } v; v.i = ((unsigned int)u) << 16; return v.f;
}
__device__ __forceinline__ ushort_t f2bf(float f) {
    union { float f; unsigned int i; } v; v.f = f;
    unsigned int x = v.i;
    x += 0x7fffu + ((x >> 16) & 1u);
    return (ushort_t)(x >> 16);
}
__device__ __forceinline__ float silu_f(float x) { return x / (1.f + __expf(-x)); }
__device__ __forceinline__ float softplus_f(float x) {
    return x > 20.f ? x : __logf(1.f + __expf(x));
}
__device__ __forceinline__ void cvt8(const float* src, ushort_t* dst) {
    floatx4 lo = *(const floatx4*)src, hi = *(const floatx4*)(src + 4);
    dst[0] = f2bf(lo.x); dst[1] = f2bf(lo.y); dst[2] = f2bf(lo.z); dst[3] = f2bf(lo.w);
    dst[4] = f2bf(hi.x); dst[5] = f2bf(hi.y); dst[6] = f2bf(hi.z); dst[7] = f2bf(hi.w);
}

#define GSTR 40
#define XSTR 130

// ---------------------------------------------------------------------------
// K1: in_proj GEMM (x half, fp32 inputs cvt-during-staging) + fused causal
// conv + SiLU. Grid (64, 8). GEMM 128x128 -> X in LDS -> conv rows 3..127
// -> xc; rows 0..2 & 125..127 dumped to xbnd for K2's boundary prologue.
// ---------------------------------------------------------------------------
__global__ __launch_bounds__(256) void gemm_conv_kernel(
    const float* __restrict__ A, const float* __restrict__ Bw,
    const float* __restrict__ cw, const float* __restrict__ cb,
    ushort_t* __restrict__ xc, ushort_t* __restrict__ xbnd)
{
    __shared__ __align__(16) ushort_t lds[128 * XSTR];   // 33,280 B
    ushort_t* As = lds;                    // [128][GSTR] staging
    ushort_t* Bs = lds + 128 * GSTR;       // total 20,480 B < 33,280
    const int tid = threadIdx.x;
    const int ti = blockIdx.x;
    const int m0 = ti * 128, n0 = blockIdx.y * 128;
    const int wave = tid >> 6, lane = tid & 63;
    const int quad = lane >> 4, lrow = lane & 15;
    const int wr = (wave >> 1) * 64, wc = (wave & 1) * 64;
    const int srow = tid >> 2;
    const int scol = (tid & 3) * 8;

    floatx4 acc[4][4];
#pragma unroll
    for (int i = 0; i < 4; i++)
#pragma unroll
        for (int j = 0; j < 4; j++) acc[i][j] = floatx4{0, 0, 0, 0};

    for (int k0 = 0; k0 < DM; k0 += 32) {
        ushort_t a0[8], a1[8], b0[8], b1[8];
        cvt8(&A[(size_t)(m0 + srow) * DM + k0 + scol], a0);
        cvt8(&A[(size_t)(m0 + 64 + srow) * DM + k0 + scol], a1);
        cvt8(&Bw[(size_t)(n0 + srow) * DM + k0 + scol], b0);
        cvt8(&Bw[(size_t)(n0 + 64 + srow) * DM + k0 + scol], b1);
        __syncthreads();
        *(uint4v*)&As[srow * GSTR + scol] = *(const uint4v*)a0;
        *(uint4v*)&As[(64 + srow) * GSTR + scol] = *(const uint4v*)a1;
        *(uint4v*)&Bs[srow * GSTR + scol] = *(const uint4v*)b0;
        *(uint4v*)&Bs[(64 + srow) * GSTR + scol] = *(const uint4v*)b1;
        __syncthreads();
        short8 af[4], bfr[4];
#pragma unroll
        for (int i = 0; i < 4; i++)
            af[i] = *(const short8*)&As[(wr + i * 16 + lrow) * GSTR + quad * 8];
#pragma unroll
        for (int j = 0; j < 4; j++)
            bfr[j] = *(const short8*)&Bs[(wc + j * 16 + lrow) * GSTR + quad * 8];
#pragma unroll
        for (int i = 0; i < 4; i++)
#pragma unroll
            for (int j = 0; j < 4; j++)
                acc[i][j] = __builtin_amdgcn_mfma_f32_16x16x32_bf16(af[i], bfr[j], acc[i][j], 0, 0, 0);
    }
    __syncthreads();   // all fragment reads done before X overlay

    // acc -> X (bf16) in LDS, stride XSTR
#pragma unroll
    for (int i = 0; i < 4; i++)
#pragma unroll
        for (int j = 0; j < 4; j++)
#pragma unroll
            for (int r = 0; r < 4; r++)
                lds[(wr + i * 16 + quad * 4 + r) * XSTR + (wc + j * 16 + lrow)] =
                    f2bf(acc[i][j][r]);
    __syncthreads();

    // conv rows 3..127 (rows 0..2 need the previous tile -> K2 prologue)
    {
        const int c = tid & 127, h = tid >> 7;
        const int d = n0 + c;
        floatx4 wv = *(const floatx4*)&cw[d * 4];
        const float bs = cb[d];
        const int rs = h ? 64 : 3;
        const int re = h ? 128 : 64;
        float a0 = bf2f(lds[(rs - 3) * XSTR + c]);
        float a1 = bf2f(lds[(rs - 2) * XSTR + c]);
        float a2 = bf2f(lds[(rs - 1) * XSTR + c]);
#pragma unroll 4
        for (int r = rs; r < re; ++r) {
            float a3 = bf2f(lds[r * XSTR + c]);
            float v = bs + wv.x * a0 + wv.y * a1 + wv.z * a2 + wv.w * a3;
            xc[(size_t)(m0 + r) * DI + d] = f2bf(silu_f(v));
            a0 = a1; a1 = a2; a2 = a3;
        }
    }
    // boundary x rows: slots 0..2 = rows 0..2; slots 3..5 = rows 125..127
    if (tid < 128) {
#pragma unroll
        for (int s = 0; s < 6; s++) {
            int r = (s < 3) ? s : (122 + s);
            xbnd[((size_t)ti * 6 + s) * DI + n0 + tid] = lds[r * XSTR + tid];
        }
    }
}

// ---------------------------------------------------------------------------
// K2: x_proj single-pass GEMM (K=1024) + boundary-conv prologue.
// Grid 256 (m-tiles of 32 rows). Blocks with bx%4==0 first complete xc rows
// m0..m0+2 from xbnd (exactly the rows only they read). B staged from fp32.
// ---------------------------------------------------------------------------
__global__ __launch_bounds__(256) void gemm_xproj_kernel(
    const ushort_t* __restrict__ xbnd, const float* __restrict__ cw,
    const float* __restrict__ cb,
    ushort_t* __restrict__ A /*xc*/, const float* __restrict__ Bw,
    ushort_t* __restrict__ xdbl_bf, float* __restrict__ cl)
{
    __shared__ __align__(16) ushort_t As[32 * 40];
    __shared__ __align__(16) ushort_t Bs[64 * 40];
    const int tid = threadIdx.x;
    const int bx = blockIdx.x;
    const int m0 = bx * 32;

    if ((bx & 3) == 0) {   // boundary prologue: xc rows m0..m0+2
        const int ti = bx >> 2;            // 0..63
        const int d0 = tid * 4;
        const bool bstart = (ti & 15) == 0;
        float v[6][4];
#pragma unroll
        for (int s = 0; s < 3; s++) {
            if (bstart) {
#pragma unroll
                for (int q = 0; q < 4; q++) v[s][q] = 0.f;
            } else {
                ushort_t t[4];
                *(uint2*)t = *(const uint2*)&xbnd[((size_t)(ti - 1) * 6 + 3 + s) * DI + d0];
#pragma unroll
                for (int q = 0; q < 4; q++) v[s][q] = bf2f(t[q]);
            }
        }
#pragma unroll
        for (int s = 0; s < 3; s++) {
            ushort_t t[4];
            *(uint2*)t = *(const uint2*)&xbnd[((size_t)ti * 6 + s) * DI + d0];
#pragma unroll
            for (int q = 0; q < 4; q++) v[3 + s][q] = bf2f(t[q]);
        }
        floatx4 b4 = *(const floatx4*)&cb[d0];
        floatx4 wq[4];
#pragma unroll
        for (int q = 0; q < 4; q++) wq[q] = *(const floatx4*)&cw[(d0 + q) * 4];
#pragma unroll
        for (int rr = 0; rr < 3; rr++) {
            ushort_t o[4];
#pragma unroll
            for (int q = 0; q < 4; q++) {
                float a = b4[q];
#pragma unroll
                for (int k = 0; k < 4; k++) a += wq[q][k] * v[rr + k][q];
                o[q] = f2bf(silu_f(a));
            }
            *(uint2*)&A[((size_t)(m0 + rr)) * DI + d0] = *(const uint2*)o;
        }
    }
    __syncthreads();   // xc writes drained (vmcnt) & visible to this block

    const int wave = tid >> 6, lane = tid & 63;
    const int quad = lane >> 4, lrow = lane & 15;
    const int msub = (wave & 1) * 16;
    const int nc0 = (wave >> 1) * 32;
    const int arow = tid >> 3, ac4 = (tid & 7) * 4;
    const int brow = tid >> 2, bc8 = (tid & 3) * 8;

    floatx4 acc[2] = {floatx4{0, 0, 0, 0}, floatx4{0, 0, 0, 0}};

    for (int k0 = 0; k0 < DI; k0 += 32) {
        uint2 a = *(const uint2*)&A[(size_t)(m0 + arow) * DI + k0 + ac4];
        ushort_t bt[8];
        cvt8(&Bw[(size_t)brow * DI + k0 + bc8], bt);
        __syncthreads();
        *(uint2*)&As[arow * 40 + ac4] = a;
        *(uint4v*)&Bs[brow * 40 + bc8] = *(const uint4v*)bt;
        __syncthreads();
        short8 af = *(const short8*)&As[(msub + lrow) * 40 + quad * 8];
        short8 b0 = *(const short8*)&Bs[(nc0 + lrow) * 40 + quad * 8];
        short8 b1 = *(const short8*)&Bs[(nc0 + 16 + lrow) * 40 + quad * 8];
        acc[0] = __builtin_amdgcn_mfma_f32_16x16x32_bf16(af, b0, acc[0], 0, 0, 0);
        acc[1] = __builtin_amdgcn_mfma_f32_16x16x32_bf16(af, b1, acc[1], 0, 0, 0);
    }
#pragma unroll
    for (int j = 0; j < 2; j++)
#pragma unroll
        for (int r = 0; r < 4; r++) {
            int row = m0 + msub + quad * 4 + r;
            int col = nc0 + j * 16 + lrow;
            xdbl_bf[(size_t)row * 64 + col] = f2bf(acc[j][r]);
            if ((row & (L_ - 1)) == L_ - 1 && col >= 48)
                cl[(row >> 11) * 16 + col - 48] = acc[j][r];
        }
}

// ---------------------------------------------------------------------------
// K3: fused dt_proj-GEMM + chunked scan pass 1.
// Grid 2048: bx = c(32) | dq(16) | b(4). dt_proj_w staged from fp32.
// ---------------------------------------------------------------------------
#define DSTR2 68   // Dl row stride (64 + 4 pad)

__global__ __launch_bounds__(256) void scan_fused_kernel(
    const ushort_t* __restrict__ xdbl_bf, const float* __restrict__ dtw_f,
    const float* __restrict__ bias, const ushort_t* __restrict__ xc,
    const float* __restrict__ A_log,
    float* __restrict__ Sc, float* __restrict__ sumDg)
{
    const int bx = blockIdx.x;
    const int c  = bx & 31;
    const int dq = (bx >> 5) & 15;
    const int b  = bx >> 9;
    const int tid = threadIdx.x;
    const int n0 = dq * 64;
    const size_t row0 = (size_t)b * L_ + c * CL;

    __shared__ __align__(16) ushort_t Dl[5120];          // 10,240 B (As/Bs overlay)
    __shared__ __align__(16) ushort_t Bsh[CL][16];       //  2,048 B
    ushort_t* As = Dl;
    ushort_t* Bs = Dl + 64 * GSTR;

    {   // stage A (xdbl cols 0..31), Bs (dt_w rows, fp32->bf16), Bsh (cols 32..47)
        int row = tid >> 2, qc = (tid & 3) * 8;
        *(uint4v*)&As[row * GSTR + qc] =
            *(const uint4v*)&xdbl_bf[(row0 + row) * 64 + qc];
        ushort_t bt[8];
        cvt8(&dtw_f[(size_t)(n0 + row) * DR + qc], bt);
        *(uint4v*)&Bs[row * GSTR + qc] = *(const uint4v*)bt;
        if (tid < 128) {
            int r2 = tid >> 1, half = tid & 1;
            *(uint4v*)&Bsh[r2][half * 8] =
                *(const uint4v*)&xdbl_bf[(row0 + r2) * 64 + 32 + half * 8];
        }
    }
    __syncthreads();

    {   // fragment loads, barrier (As/Bs die), MFMA -> Dl overlay
        const int wave = tid >> 6, lane = tid & 63;
        const int quad = lane >> 4, lrow = lane & 15;
        const int wr = (wave >> 1) * 32, wc = (wave & 1) * 32;
        short8 af[2], bfr[2];
#pragma unroll
        for (int i = 0; i < 2; i++)
            af[i] = *(const short8*)&As[(wr + i * 16 + lrow) * GSTR + quad * 8];
#pragma unroll
        for (int j = 0; j < 2; j++)
            bfr[j] = *(const short8*)&Bs[(wc + j * 16 + lrow) * GSTR + quad * 8];
        __syncthreads();   // all As/Bs reads complete before Dl overlay writes
#pragma unroll
        for (int i = 0; i < 2; i++)
#pragma unroll
            for (int j = 0; j < 2; j++) {
                floatx4 a = __builtin_amdgcn_mfma_f32_16x16x32_bf16(
                    af[i], bfr[j], floatx4{0, 0, 0, 0}, 0, 0, 0);
                int dl = wc + j * 16 + lrow;
                float bs = bias[n0 + dl];
#pragma unroll
                for (int r = 0; r < 4; r++) {
                    int t = wr + i * 16 + quad * 4 + r;
                    Dl[t * DSTR2 + dl] = f2bf(softplus_f(a[r] + bs));
                }
            }
    }
    __syncthreads();

    // scan phase: thread = (dloc 64, sh 4), 4 s-states each
    const int dloc = tid & 63, sh = tid >> 6;
    const int d = n0 + dloc;
    const float Av0 = -__expf(A_log[d * DS + sh * 4]);
    float S[4] = {0.f, 0.f, 0.f, 0.f};
    float sumD = 0.f;
    size_t ub = row0 * DI + d;
#pragma unroll 4
    for (int t = 0; t < CL; ++t) {
        float delta = bf2f(Dl[t * DSTR2 + dloc]);
        float u = bf2f(xc[ub]); ub += DI;
        float du = delta * u;
        sumD += delta;
        float e  = __expf(-delta);
        float dA = __expf(delta * Av0);
        ushort_t bq[4];
        *(uint2*)bq = *(const uint2*)&Bsh[t][sh * 4];
#pragma unroll
        for (int j = 0; j < 4; j++) {
            float Bv = bf2f(bq[j]);
            S[j] = __builtin_fmaf(dA, S[j], du * Bv);
            dA *= e;
        }
    }
#pragma unroll
    for (int j = 0; j < 4; j++) {
        int s = sh * 4 + j;
        Sc[(((size_t)c * 4 + b) * 16 + s) * 1024 + d] = S[j];
    }
    if (sh == 0) sumDg[((size_t)c * 4 + b) * 1024 + d] = sumD;
}

// ---------------------------------------------------------------------------
// K4: pass 2 + gate + z_last fold. Grid 256: b(4) x dgrp(64);
// 256 thr = s(16) x dl(16). z = x_seq[last] . in_proj_w[DI+d] computed
// in-block (per-s 32-wide partials, LDS reduce).
// ---------------------------------------------------------------------------
__global__ __launch_bounds__(256) void combine_gate_kernel(
    const float* __restrict__ Sc, const float* __restrict__ sumDg,
    const float* __restrict__ A_log, const float* __restrict__ cl,
    const ushort_t* __restrict__ xc, const float* __restrict__ Dv,
    const float* __restrict__ x_seq, const float* __restrict__ in_proj_w,
    float* __restrict__ y_last)
{
    const int bx = blockIdx.x;
    const int b = bx >> 6, dgrp = bx & 63;
    const int tid = threadIdx.x;
    const int s = tid >> 4, dl = tid & 15;
    const int d = dgrp * 16 + dl;

    __shared__ float Cl[16];
    __shared__ float part[16][17];
    __shared__ float zpart[16][17];
    if (tid < 16) Cl[tid] = cl[b * 16 + tid];

    {   // z partial: k-range [32s, 32s+32)
        const float* xl = &x_seq[((size_t)b * L_ + L_ - 1) * DM];
        const float* wz = &in_proj_w[(size_t)(DI + d) * DM];
        float zp = 0.f;
#pragma unroll 8
        for (int k = s * 32; k < s * 32 + 32; k++) zp += xl[k] * wz[k];
        zpart[s][dl] = zp;
    }
    __syncthreads();

    const float Av = -__expf(A_log[d * DS + s]);
    float h = 0.f;
#pragma unroll 8
    for (int c = 0; c < CHUNK; ++c) {
        float sD = sumDg[((size_t)c * 4 + b) * 1024 + d];
        float S  = Sc[(((size_t)c * 4 + b) * 16 + s) * 1024 + d];
        h = __builtin_fmaf(__expf(Av * sD), h, S);
    }
    part[s][dl] = h * Cl[s];
    __syncthreads();
    if (tid < 16) {
        float Y = 0.f, z = 0.f;
#pragma unroll
        for (int s2 = 0; s2 < 16; s2++) { Y += part[s2][tid]; z += zpart[s2][tid]; }
        int d2 = dgrp * 16 + tid;
        float u_last = bf2f(xc[((size_t)b * L_ + L_ - 1) * DI + d2]);
        Y += u_last * Dv[d2];
        y_last[b * DI + d2] = Y * silu_f(z);
    }
}

// ---------------------------------------------------------------------------
// K5: out projection (last token only)
// ---------------------------------------------------------------------------
__global__ __launch_bounds__(64) void outproj_kernel(
    const float* __restrict__ y_last, const float* __restrict__ out_proj_w,
    float* __restrict__ out)
{
    int o = blockIdx.x;                 // 0 .. B_*DM-1
    int b = o >> 9;
    int lane = threadIdx.x;
    const float* yr = &y_last[b * DI];
    const float* wr = &out_proj_w[(size_t)(o & (DM - 1)) * DI];
    float v = 0.f;
#pragma unroll
    for (int k = 0; k < DI / 64; k++)
        v += yr[lane + k * 64] * wr[lane + k * 64];
#pragma unroll
    for (int off = 32; off > 0; off >>= 1) v += __shfl_down(v, off);
    if (lane == 0) out[o] = v;
}

// ---------------------------------------------------------------------------
extern "C" void kernel_launch(void* const* d_in, const int* in_sizes, int n_in,
                              void* d_out, int out_size, void* d_ws, size_t ws_size,
                              hipStream_t stream)
{
    const float* x_seq     = (const float*)d_in[0];
    const float* in_proj_w = (const float*)d_in[1];
    const float* conv_w    = (const float*)d_in[2];
    const float* conv_b    = (const float*)d_in[3];
    const float* x_proj_w  = (const float*)d_in[4];
    const float* dt_proj_w = (const float*)d_in[5];
    const float* dt_proj_b = (const float*)d_in[6];
    const float* A_log     = (const float*)d_in[7];
    const float* Dv        = (const float*)d_in[8];
    const float* out_proj_w= (const float*)d_in[9];
    float* out_f           = (float*)d_out;

    char* ws = (char*)d_ws;
    ushort_t* xc_bf     = (ushort_t*)(ws + 0);          // 16,777,216
    ushort_t* xdbl_bf   = (ushort_t*)(ws + 16777216);   //  1,048,576
    float*    Sc        = (float*)(ws + 17825792);      //  8,388,608
    float*    sumD      = (float*)(ws + 26214400);      //    524,288
    float*    y_last    = (float*)(ws + 26738688);      //     16,384
    float*    cl        = (float*)(ws + 26755072);      //        256
    ushort_t* xbnd      = (ushort_t*)(ws + 26756096);   //    786,432

    // 1) in_proj GEMM (fp32 in, cvt-in-staging) + fused conv/SiLU + xbnd dump
    gemm_conv_kernel<<<dim3(M_ / 128, DI / 128), 256, 0, stream>>>(
        x_seq, in_proj_w, conv_w, conv_b, xc_bf, xbnd);

    // 2) boundary-conv prologue + x_proj single-pass GEMM -> xdbl + cl
    gemm_xproj_kernel<<<M_ / 32, 256, 0, stream>>>(
        xbnd, conv_w, conv_b, xc_bf, x_proj_w, xdbl_bf, cl);

    // 3) fused dt_proj + chunked scan pass 1
    scan_fused_kernel<<<2048, 256, 0, stream>>>(
        xdbl_bf, dt_proj_w, dt_proj_b, xc_bf, A_log, Sc, sumD);

    // 4) combine + gate + z_last fold
    combine_gate_kernel<<<256, 256, 0, stream>>>(
        Sc, sumD, A_log, cl, xc_bf, Dv, x_seq, in_proj_w, y_last);

    // 5) out projection (last token only)
    outproj_kernel<<<B_ * DM, 64, 0, stream>>>(y_last, out_proj_w, out_f);
}

// Round 9
// 155.712 us; speedup vs baseline: 1.0404x; 1.0404x over previous
//
#include <hip/hip_runtime.h>

#define B_ 4
#define L_ 2048
#define DM 512
#define DI 1024
#define DS 16
#define DR 32
#define M_ (B_ * L_)

#define CHUNK 32
#define CL (L_ / CHUNK)   // 64 timesteps per chunk

typedef unsigned short ushort_t;
typedef __attribute__((ext_vector_type(8))) short short8;
typedef __attribute__((ext_vector_type(4))) float floatx4;
typedef __attribute__((ext_vector_type(4))) unsigned int uint4v;

// address-space casts for global_load_lds
#define AS1(p) ((const __attribute__((address_space(1))) void*)(p))
#define AS3(p) ((__attribute__((address_space(3))) void*)(p))

__device__ __forceinline__ float bf2f(ushort_t u) {
    union { unsigned int i; float f; } v; v.i = ((unsigned int)u) << 16; return v.f;
}
__device__ __forceinline__ ushort_t f2bf(float f) {
    union { float f; unsigned int i; } v; v.f = f;
    unsigned int x = v.i;
    x += 0x7fffu + ((x >> 16) & 1u);
    return (ushort_t)(x >> 16);
}
__device__ __forceinline__ float silu_f(float x) { return x / (1.f + __expf(-x)); }
__device__ __forceinline__ float softplus_f(float x) {
    return x > 20.f ? x : __logf(1.f + __expf(x));
}
__device__ __forceinline__ void cvt8(const float* src, ushort_t* dst) {
    floatx4 lo = *(const floatx4*)src, hi = *(const floatx4*)(src + 4);
    dst[0] = f2bf(lo.x); dst[1] = f2bf(lo.y); dst[2] = f2bf(lo.z); dst[3] = f2bf(lo.w);
    dst[4] = f2bf(hi.x); dst[5] = f2bf(hi.y); dst[6] = f2bf(hi.z); dst[7] = f2bf(hi.w);
}

#define GSTR 40
#define XSTR 130

// ---------------------------------------------------------------------------
// K0 prep: weight/input fp32->bf16 converts only (consumers use gload_lds).
// ---------------------------------------------------------------------------
#define SM0 (64 * DI)                // x_proj_w elems
#define SM1 (DI * DR)                // dt_proj_w elems
#define SM4 (M_ * DM)                // x_seq cvt
#define SM5 (DI * DM)                // in_proj_w x-half cvt
#define SMTOT (SM0 + SM1 + SM4 + SM5)
#define PREP_GRID ((SMTOT / 4 + 63) / 64)

__global__ __launch_bounds__(64) void prep_kernel(
    const float* __restrict__ x_seq, const float* __restrict__ in_proj_w,
    const float* __restrict__ x_proj_w, ushort_t* __restrict__ c_xprojw,
    const float* __restrict__ dt_proj_w, ushort_t* __restrict__ c_dtprojw,
    ushort_t* __restrict__ xs_bf, ushort_t* __restrict__ wx_bf)
{
    int i = (blockIdx.x * 64 + threadIdx.x) * 4;
    if (i < SM0) {
        floatx4 v = *(const floatx4*)&x_proj_w[i];
        ushort_t o[4] = {f2bf(v.x), f2bf(v.y), f2bf(v.z), f2bf(v.w)};
        *(uint2*)&c_xprojw[i] = *(const uint2*)o;
    } else if ((i -= SM0) < SM1) {
        floatx4 v = *(const floatx4*)&dt_proj_w[i];
        ushort_t o[4] = {f2bf(v.x), f2bf(v.y), f2bf(v.z), f2bf(v.w)};
        *(uint2*)&c_dtprojw[i] = *(const uint2*)o;
    } else if ((i -= SM1) < SM4) {
        floatx4 v = *(const floatx4*)&x_seq[i];
        ushort_t o[4] = {f2bf(v.x), f2bf(v.y), f2bf(v.z), f2bf(v.w)};
        *(uint2*)&xs_bf[i] = *(const uint2*)o;
    } else if ((i -= SM4) < SM5) {
        floatx4 v = *(const floatx4*)&in_proj_w[i];   // rows 0..DI-1 (x half)
        ushort_t o[4] = {f2bf(v.x), f2bf(v.y), f2bf(v.z), f2bf(v.w)};
        *(uint2*)&wx_bf[i] = *(const uint2*)o;
    }
}

// ---------------------------------------------------------------------------
// K1: in_proj GEMM (bf16, gload_lds, BK=64, XOR-swizzled LDS) + fused causal
// conv + SiLU. LDS[row][c] holds M[row][c ^ 8*(row&7)] (linear dest, source
// column permuted — involution; reads apply the same XOR). Rows 0..2 &
// 125..127 of X dumped to xbnd for K2's boundary prologue.
// ---------------------------------------------------------------------------
__global__ __launch_bounds__(256) void gemm_conv_kernel(
    const ushort_t* __restrict__ A, const ushort_t* __restrict__ Bw,
    const float* __restrict__ cw, const float* __restrict__ cb,
    ushort_t* __restrict__ xc, ushort_t* __restrict__ xbnd)
{
    __shared__ __align__(16) ushort_t lds[128 * XSTR];   // 33,280 B
    ushort_t* As = lds;                    // [128][64] swizzled
    ushort_t* Bs = lds + 128 * 64;         // [128][64] swizzled; 32 KB total
    const int tid = threadIdx.x;
    const int ti = blockIdx.x;
    const int m0 = ti * 128, n0 = blockIdx.y * 128;
    const int wave = tid >> 6, lane = tid & 63;
    const int quad = lane >> 4, lrow = lane & 15;
    const int wr = (wave >> 1) * 64, wc = (wave & 1) * 64;

    // staging: issue i covers rows i*32 + (tid>>3); dest col linear, source
    // col = dest col ^ 8*(row&7)
    const int grow = tid >> 3;                        // 0..31
    const int dcol = (tid & 7) * 8;                   // dest elem col
    const int swzc = dcol ^ (8 * (grow & 7));         // source elem col

    floatx4 acc[4][4];
#pragma unroll
    for (int i = 0; i < 4; i++)
#pragma unroll
        for (int j = 0; j < 4; j++) acc[i][j] = floatx4{0, 0, 0, 0};

    for (int k0 = 0; k0 < DM; k0 += 64) {
#pragma unroll
        for (int i = 0; i < 4; i++) {
            int row = i * 32 + grow;
            __builtin_amdgcn_global_load_lds(
                AS1(&A[(size_t)(m0 + row) * DM + k0 + swzc]),
                AS3(&As[row * 64 + dcol]), 16, 0, 0);
            __builtin_amdgcn_global_load_lds(
                AS1(&Bw[(size_t)(n0 + row) * DM + k0 + swzc]),
                AS3(&Bs[row * 64 + dcol]), 16, 0, 0);
        }
        __syncthreads();
#pragma unroll
        for (int ks = 0; ks < 2; ks++) {
            short8 af[4], bfr[4];
#pragma unroll
            for (int i = 0; i < 4; i++) {
                int row = wr + i * 16 + lrow;
                af[i] = *(const short8*)&As[row * 64 +
                        ((ks * 32 + quad * 8) ^ (8 * (row & 7)))];
            }
#pragma unroll
            for (int j = 0; j < 4; j++) {
                int row = wc + j * 16 + lrow;
                bfr[j] = *(const short8*)&Bs[row * 64 +
                         ((ks * 32 + quad * 8) ^ (8 * (row & 7)))];
            }
#pragma unroll
            for (int i = 0; i < 4; i++)
#pragma unroll
                for (int j = 0; j < 4; j++)
                    acc[i][j] = __builtin_amdgcn_mfma_f32_16x16x32_bf16(
                        af[i], bfr[j], acc[i][j], 0, 0, 0);
        }
        __syncthreads();   // fragment reads done before next staging / overlay
    }

    // acc -> X (bf16) in LDS, stride XSTR
#pragma unroll
    for (int i = 0; i < 4; i++)
#pragma unroll
        for (int j = 0; j < 4; j++)
#pragma unroll
            for (int r = 0; r < 4; r++)
                lds[(wr + i * 16 + quad * 4 + r) * XSTR + (wc + j * 16 + lrow)] =
                    f2bf(acc[i][j][r]);
    __syncthreads();

    // conv rows 3..127 (rows 0..2 need the previous tile -> K2 prologue)
    {
        const int c = tid & 127, h = tid >> 7;
        const int d = n0 + c;
        floatx4 wv = *(const floatx4*)&cw[d * 4];
        const float bs = cb[d];
        const int rs = h ? 64 : 3;
        const int re = h ? 128 : 64;
        float a0 = bf2f(lds[(rs - 3) * XSTR + c]);
        float a1 = bf2f(lds[(rs - 2) * XSTR + c]);
        float a2 = bf2f(lds[(rs - 1) * XSTR + c]);
#pragma unroll 4
        for (int r = rs; r < re; ++r) {
            float a3 = bf2f(lds[r * XSTR + c]);
            float v = bs + wv.x * a0 + wv.y * a1 + wv.z * a2 + wv.w * a3;
            xc[(size_t)(m0 + r) * DI + d] = f2bf(silu_f(v));
            a0 = a1; a1 = a2; a2 = a3;
        }
    }
    // boundary x rows: slots 0..2 = rows 0..2; slots 3..5 = rows 125..127
    if (tid < 128) {
#pragma unroll
        for (int s = 0; s < 6; s++) {
            int r = (s < 3) ? s : (122 + s);
            xbnd[((size_t)ti * 6 + s) * DI + n0 + tid] = lds[r * XSTR + tid];
        }
    }
}

// ---------------------------------------------------------------------------
// K2: x_proj single-pass GEMM (K=1024, bf16 weights) + boundary-conv
// prologue in blocks with bx%4==0 (exactly the rows only they read).
// ---------------------------------------------------------------------------
__global__ __launch_bounds__(256) void gemm_xproj_kernel(
    const ushort_t* __restrict__ xbnd, const float* __restrict__ cw,
    const float* __restrict__ cb,
    ushort_t* __restrict__ A /*xc*/, const ushort_t* __restrict__ Bw,
    ushort_t* __restrict__ xdbl_bf, float* __restrict__ cl)
{
    __shared__ __align__(16) ushort_t As[32 * 40];
    __shared__ __align__(16) ushort_t Bs[64 * 40];
    const int tid = threadIdx.x;
    const int bx = blockIdx.x;
    const int m0 = bx * 32;

    if ((bx & 3) == 0) {   // boundary prologue: xc rows m0..m0+2
        const int ti = bx >> 2;            // 0..63
        const int d0 = tid * 4;
        const bool bstart = (ti & 15) == 0;
        float v[6][4];
#pragma unroll
        for (int s = 0; s < 3; s++) {
            if (bstart) {
#pragma unroll
                for (int q = 0; q < 4; q++) v[s][q] = 0.f;
            } else {
                ushort_t t[4];
                *(uint2*)t = *(const uint2*)&xbnd[((size_t)(ti - 1) * 6 + 3 + s) * DI + d0];
#pragma unroll
                for (int q = 0; q < 4; q++) v[s][q] = bf2f(t[q]);
            }
        }
#pragma unroll
        for (int s = 0; s < 3; s++) {
            ushort_t t[4];
            *(uint2*)t = *(const uint2*)&xbnd[((size_t)ti * 6 + s) * DI + d0];
#pragma unroll
            for (int q = 0; q < 4; q++) v[3 + s][q] = bf2f(t[q]);
        }
        floatx4 b4 = *(const floatx4*)&cb[d0];
        floatx4 wq[4];
#pragma unroll
        for (int q = 0; q < 4; q++) wq[q] = *(const floatx4*)&cw[(d0 + q) * 4];
#pragma unroll
        for (int rr = 0; rr < 3; rr++) {
            ushort_t o[4];
#pragma unroll
            for (int q = 0; q < 4; q++) {
                float a = b4[q];
#pragma unroll
                for (int k = 0; k < 4; k++) a += wq[q][k] * v[rr + k][q];
                o[q] = f2bf(silu_f(a));
            }
            *(uint2*)&A[((size_t)(m0 + rr)) * DI + d0] = *(const uint2*)o;
        }
    }
    __syncthreads();   // xc writes drained & visible within this block

    const int wave = tid >> 6, lane = tid & 63;
    const int quad = lane >> 4, lrow = lane & 15;
    const int msub = (wave & 1) * 16;
    const int nc0 = (wave >> 1) * 32;
    const int arow = tid >> 3, ac4 = (tid & 7) * 4;
    const int brow = tid >> 2, bc8 = (tid & 3) * 8;

    floatx4 acc[2] = {floatx4{0, 0, 0, 0}, floatx4{0, 0, 0, 0}};

    for (int k0 = 0; k0 < DI; k0 += 32) {
        uint2 a = *(const uint2*)&A[(size_t)(m0 + arow) * DI + k0 + ac4];
        uint4v b = *(const uint4v*)&Bw[(size_t)brow * DI + k0 + bc8];
        __syncthreads();
        *(uint2*)&As[arow * 40 + ac4] = a;
        *(uint4v*)&Bs[brow * 40 + bc8] = b;
        __syncthreads();
        short8 af = *(const short8*)&As[(msub + lrow) * 40 + quad * 8];
        short8 b0 = *(const short8*)&Bs[(nc0 + lrow) * 40 + quad * 8];
        short8 b1 = *(const short8*)&Bs[(nc0 + 16 + lrow) * 40 + quad * 8];
        acc[0] = __builtin_amdgcn_mfma_f32_16x16x32_bf16(af, b0, acc[0], 0, 0, 0);
        acc[1] = __builtin_amdgcn_mfma_f32_16x16x32_bf16(af, b1, acc[1], 0, 0, 0);
    }
#pragma unroll
    for (int j = 0; j < 2; j++)
#pragma unroll
        for (int r = 0; r < 4; r++) {
            int row = m0 + msub + quad * 4 + r;
            int col = nc0 + j * 16 + lrow;
            xdbl_bf[(size_t)row * 64 + col] = f2bf(acc[j][r]);
            if ((row & (L_ - 1)) == L_ - 1 && col >= 48)
                cl[(row >> 11) * 16 + col - 48] = acc[j][r];
        }
}

// ---------------------------------------------------------------------------
// K3: fused dt_proj-GEMM + chunked scan pass 1.
// Grid 2048: bx = c(32) | dq(16) | b(4). bf16 weights (c_dtprojw).
// ---------------------------------------------------------------------------
#define DSTR2 68   // Dl row stride (64 + 4 pad)

__global__ __launch_bounds__(256) void scan_fused_kernel(
    const ushort_t* __restrict__ xdbl_bf, const ushort_t* __restrict__ dtw,
    const float* __restrict__ bias, const ushort_t* __restrict__ xc,
    const float* __restrict__ A_log,
    float* __restrict__ Sc, float* __restrict__ sumDg)
{
    const int bx = blockIdx.x;
    const int c  = bx & 31;
    const int dq = (bx >> 5) & 15;
    const int b  = bx >> 9;
    const int tid = threadIdx.x;
    const int n0 = dq * 64;
    const size_t row0 = (size_t)b * L_ + c * CL;

    __shared__ __align__(16) ushort_t Dl[5120];          // 10,240 B (As/Bs overlay)
    __shared__ __align__(16) ushort_t Bsh[CL][16];       //  2,048 B
    ushort_t* As = Dl;
    ushort_t* Bs = Dl + 64 * GSTR;

    {   // stage A (xdbl cols 0..31), Bs (dt_w rows), Bsh (cols 32..47) — all bf16
        int row = tid >> 2, qc = (tid & 3) * 8;
        *(uint4v*)&As[row * GSTR + qc] =
            *(const uint4v*)&xdbl_bf[(row0 + row) * 64 + qc];
        *(uint4v*)&Bs[row * GSTR + qc] =
            *(const uint4v*)&dtw[(size_t)(n0 + row) * DR + qc];
        if (tid < 128) {
            int r2 = tid >> 1, half = tid & 1;
            *(uint4v*)&Bsh[r2][half * 8] =
                *(const uint4v*)&xdbl_bf[(row0 + r2) * 64 + 32 + half * 8];
        }
    }
    __syncthreads();

    {   // fragment loads, barrier (As/Bs die), MFMA -> Dl overlay
        const int wave = tid >> 6, lane = tid & 63;
        const int quad = lane >> 4, lrow = lane & 15;
        const int wr = (wave >> 1) * 32, wc = (wave & 1) * 32;
        short8 af[2], bfr[2];
#pragma unroll
        for (int i = 0; i < 2; i++)
            af[i] = *(const short8*)&As[(wr + i * 16 + lrow) * GSTR + quad * 8];
#pragma unroll
        for (int j = 0; j < 2; j++)
            bfr[j] = *(const short8*)&Bs[(wc + j * 16 + lrow) * GSTR + quad * 8];
        __syncthreads();   // all As/Bs reads complete before Dl overlay writes
#pragma unroll
        for (int i = 0; i < 2; i++)
#pragma unroll
            for (int j = 0; j < 2; j++) {
                floatx4 a = __builtin_amdgcn_mfma_f32_16x16x32_bf16(
                    af[i], bfr[j], floatx4{0, 0, 0, 0}, 0, 0, 0);
                int dl = wc + j * 16 + lrow;
                float bs = bias[n0 + dl];
#pragma unroll
                for (int r = 0; r < 4; r++) {
                    int t = wr + i * 16 + quad * 4 + r;
                    Dl[t * DSTR2 + dl] = f2bf(softplus_f(a[r] + bs));
                }
            }
    }
    __syncthreads();

    // scan phase: thread = (dloc 64, sh 4), 4 s-states each
    const int dloc = tid & 63, sh = tid >> 6;
    const int d = n0 + dloc;
    const float Av0 = -__expf(A_log[d * DS + sh * 4]);
    float S[4] = {0.f, 0.f, 0.f, 0.f};
    float sumD = 0.f;
    size_t ub = row0 * DI + d;
#pragma unroll 4
    for (int t = 0; t < CL; ++t) {
        float delta = bf2f(Dl[t * DSTR2 + dloc]);
        float u = bf2f(xc[ub]); ub += DI;
        float du = delta * u;
        sumD += delta;
        float e  = __expf(-delta);
        float dA = __expf(delta * Av0);
        ushort_t bq[4];
        *(uint2*)bq = *(const uint2*)&Bsh[t][sh * 4];
#pragma unroll
        for (int j = 0; j < 4; j++) {
            float Bv = bf2f(bq[j]);
            S[j] = __builtin_fmaf(dA, S[j], du * Bv);
            dA *= e;
        }
    }
#pragma unroll
    for (int j = 0; j < 4; j++) {
        int s = sh * 4 + j;
        Sc[(((size_t)c * 4 + b) * 16 + s) * 1024 + d] = S[j];
    }
    if (sh == 0) sumDg[((size_t)c * 4 + b) * 1024 + d] = sumD;
}

// ---------------------------------------------------------------------------
// K4: pass 2 + gate + z_last fold. Grid 256: b(4) x dgrp(64);
// 256 thr = s(16) x dl(16). z computed in-block (per-s partials, LDS reduce).
// ---------------------------------------------------------------------------
__global__ __launch_bounds__(256) void combine_gate_kernel(
    const float* __restrict__ Sc, const float* __restrict__ sumDg,
    const float* __restrict__ A_log, const float* __restrict__ cl,
    const ushort_t* __restrict__ xc, const float* __restrict__ Dv,
    const float* __restrict__ x_seq, const float* __restrict__ in_proj_w,
    float* __restrict__ y_last)
{
    const int bx = blockIdx.x;
    const int b = bx >> 6, dgrp = bx & 63;
    const int tid = threadIdx.x;
    const int s = tid >> 4, dl = tid & 15;
    const int d = dgrp * 16 + dl;

    __shared__ float Cl[16];
    __shared__ float part[16][17];
    __shared__ float zpart[16][17];
    if (tid < 16) Cl[tid] = cl[b * 16 + tid];

    {   // z partial: k-range [32s, 32s+32)
        const float* xl = &x_seq[((size_t)b * L_ + L_ - 1) * DM];
        const float* wz = &in_proj_w[(size_t)(DI + d) * DM];
        float zp = 0.f;
#pragma unroll 8
        for (int k = s * 32; k < s * 32 + 32; k++) zp += xl[k] * wz[k];
        zpart[s][dl] = zp;
    }
    __syncthreads();

    const float Av = -__expf(A_log[d * DS + s]);
    float h = 0.f;
#pragma unroll 8
    for (int c = 0; c < CHUNK; ++c) {
        float sD = sumDg[((size_t)c * 4 + b) * 1024 + d];
        float S  = Sc[(((size_t)c * 4 + b) * 16 + s) * 1024 + d];
        h = __builtin_fmaf(__expf(Av * sD), h, S);
    }
    part[s][dl] = h * Cl[s];
    __syncthreads();
    if (tid < 16) {
        float Y = 0.f, z = 0.f;
#pragma unroll
        for (int s2 = 0; s2 < 16; s2++) { Y += part[s2][tid]; z += zpart[s2][tid]; }
        int d2 = dgrp * 16 + tid;
        float u_last = bf2f(xc[((size_t)b * L_ + L_ - 1) * DI + d2]);
        Y += u_last * Dv[d2];
        y_last[b * DI + d2] = Y * silu_f(z);
    }
}

// ---------------------------------------------------------------------------
// K5: out projection (last token only)
// ---------------------------------------------------------------------------
__global__ __launch_bounds__(64) void outproj_kernel(
    const float* __restrict__ y_last, const float* __restrict__ out_proj_w,
    float* __restrict__ out)
{
    int o = blockIdx.x;                 // 0 .. B_*DM-1
    int b = o >> 9;
    int lane = threadIdx.x;
    const float* yr = &y_last[b * DI];
    const float* wr = &out_proj_w[(size_t)(o & (DM - 1)) * DI];
    float v = 0.f;
#pragma unroll
    for (int k = 0; k < DI / 64; k++)
        v += yr[lane + k * 64] * wr[lane + k * 64];
#pragma unroll
    for (int off = 32; off > 0; off >>= 1) v += __shfl_down(v, off);
    if (lane == 0) out[o] = v;
}

// ---------------------------------------------------------------------------
extern "C" void kernel_launch(void* const* d_in, const int* in_sizes, int n_in,
                              void* d_out, int out_size, void* d_ws, size_t ws_size,
                              hipStream_t stream)
{
    const float* x_seq     = (const float*)d_in[0];
    const float* in_proj_w = (const float*)d_in[1];
    const float* conv_w    = (const float*)d_in[2];
    const float* conv_b    = (const float*)d_in[3];
    const float* x_proj_w  = (const float*)d_in[4];
    const float* dt_proj_w = (const float*)d_in[5];
    const float* dt_proj_b = (const float*)d_in[6];
    const float* A_log     = (const float*)d_in[7];
    const float* Dv        = (const float*)d_in[8];
    const float* out_proj_w= (const float*)d_in[9];
    float* out_f           = (float*)d_out;

    char* ws = (char*)d_ws;
    ushort_t* xc_bf     = (ushort_t*)(ws + 0);          // 16,777,216
    ushort_t* xdbl_bf   = (ushort_t*)(ws + 16777216);   //  1,048,576
    float*    Sc        = (float*)(ws + 17825792);      //  8,388,608
    float*    sumD      = (float*)(ws + 26214400);      //    524,288
    float*    y_last    = (float*)(ws + 26738688);      //     16,384
    float*    cl        = (float*)(ws + 26755072);      //        256
    ushort_t* xbnd      = (ushort_t*)(ws + 26756096);   //    786,432
    ushort_t* c_xprojw  = (ushort_t*)(ws + 27542528);   //    131,072
    ushort_t* c_dtprojw = (ushort_t*)(ws + 27673600);   //     65,536
    ushort_t* xs_bf     = (ushort_t*)(ws + 27739136);   //  8,388,608
    ushort_t* wx_bf     = (ushort_t*)(ws + 36127744);   //  1,048,576

    // 0) prep: fp32->bf16 converts
    prep_kernel<<<PREP_GRID, 64, 0, stream>>>(
        x_seq, in_proj_w, x_proj_w, c_xprojw, dt_proj_w, c_dtprojw, xs_bf, wx_bf);

    // 1) in_proj GEMM (BK=64, swizzled gload_lds) + fused conv/SiLU + xbnd
    gemm_conv_kernel<<<dim3(M_ / 128, DI / 128), 256, 0, stream>>>(
        xs_bf, wx_bf, conv_w, conv_b, xc_bf, xbnd);

    // 2) boundary-conv prologue + x_proj single-pass GEMM -> xdbl + cl
    gemm_xproj_kernel<<<M_ / 32, 256, 0, stream>>>(
        xbnd, conv_w, conv_b, xc_bf, c_xprojw, xdbl_bf, cl);

    // 3) fused dt_proj + chunked scan pass 1
    scan_fused_kernel<<<2048, 256, 0, stream>>>(
        xdbl_bf, c_dtprojw, dt_proj_b, xc_bf, A_log, Sc, sumD);

    // 4) combine + gate + z_last fold
    combine_gate_kernel<<<256, 256, 0, stream>>>(
        Sc, sumD, A_log, cl, xc_bf, Dv, x_seq, in_proj_w, y_last);

    // 5) out projection (last token only)
    outproj_kernel<<<B_ * DM, 64, 0, stream>>>(y_last, out_proj_w, out_f);
}